// Round 13
// baseline (360.278 us; speedup 1.0000x reference)
//
#include <hip/hip_runtime.h>
#include <hip/hip_bf16.h>
#include <cstdint>
#include <cstddef>

// ---------------- problem constants ----------------
#define DTOK 1024      // embed dim
#define IFF  512       // ffn intermediate
#define NEXP 7         // routed experts
#define TTOK 16384     // B*S tokens
#define CAP  (2*TTOK + NEXP*128)   // padded routed slot capacity = 33664 (263 tiles of 128)
#define CAPX (CAP + TTOK)          // + shared segment (expert 7, identity) = 50048

typedef __bf16 v8bf  __attribute__((ext_vector_type(8)));
typedef float  f32x4 __attribute__((ext_vector_type(4)));

#define AS1 __attribute__((address_space(1)))
#define AS3 __attribute__((address_space(3)))

// ---------------- small prep kernels ----------------

// Router fused with x->bf16 cast. One wave per token; logits in full fp32
// (bf16 x would flip near-tie top-k picks). Reads x as float4 (coalesced),
// writes xb as 4x bf16 per lane (8B, coalesced).
__global__ __launch_bounds__(256) void router_cast_kernel(
    const float4* __restrict__ x4, const float* __restrict__ w_r,
    const float* __restrict__ b_r, const float* __restrict__ rb,
    __bf16* __restrict__ xb, int* __restrict__ top_i, float* __restrict__ top_w) {
    typedef __bf16 v4bf __attribute__((ext_vector_type(4)));
    const int wid = threadIdx.x >> 6, lane = threadIdx.x & 63;
    const int t = blockIdx.x * 4 + wid;
    float acc[NEXP] = {0.f,0.f,0.f,0.f,0.f,0.f,0.f};
    #pragma unroll
    for (int it = 0; it < 4; ++it) {
        const int c = it * 64 + lane;              // float4 index within row
        float4 xv = x4[(size_t)t * 256 + c];
        v4bf o; o[0] = (__bf16)xv.x; o[1] = (__bf16)xv.y;
                o[2] = (__bf16)xv.z; o[3] = (__bf16)xv.w;
        *reinterpret_cast<v4bf*>(xb + (size_t)t * DTOK + c * 4) = o;
        const float* wr = w_r + (size_t)c * 4 * NEXP;   // w_r is [1024][7], 28KB total (cached)
        #pragma unroll
        for (int e = 0; e < NEXP; ++e)
            acc[e] += xv.x * wr[e] + xv.y * wr[NEXP + e]
                    + xv.z * wr[2 * NEXP + e] + xv.w * wr[3 * NEXP + e];
    }
    #pragma unroll
    for (int e = 0; e < NEXP; ++e)
        #pragma unroll
        for (int off = 32; off; off >>= 1) acc[e] += __shfl_xor(acc[e], off);
    if (lane == 0) {
        float p[NEXP];
        #pragma unroll
        for (int e = 0; e < NEXP; ++e) p[e] = 1.f / (1.f + expf(-(acc[e] + b_r[e] + rb[e])));
        int i0 = 0;
        #pragma unroll
        for (int e = 1; e < NEXP; ++e) if (p[e] > p[i0]) i0 = e;   // ties -> lowest idx
        int i1 = -1;
        #pragma unroll
        for (int e = 0; e < NEXP; ++e) if (e != i0 && (i1 < 0 || p[e] > p[i1])) i1 = e;
        float s = p[i0] + p[i1];
        top_i[2 * t] = i0; top_i[2 * t + 1] = i1;
        top_w[2 * t] = p[i0] / s; top_w[2 * t + 1] = p[i1] / s;
    }
}

// B1[e][r][k] = W[k][c], c=(r>>5)*16+(r&15), gate if (r&31)<16 else up.
// Coalesced via LDS transpose. block = (kh in [0,2), j in [0,32), e in [0,8))
__global__ __launch_bounds__(256) void build_B1t(
    const float* __restrict__ r_gate, const float* __restrict__ r_up,
    const float* __restrict__ sh_gate, const float* __restrict__ sh_up,
    __bf16* __restrict__ B1) {
    const int kh = blockIdx.x, j = blockIdx.y, e = blockIdx.z;
    const float* G = (e < NEXP) ? (r_gate + (size_t)e * (DTOK * IFF)) : sh_gate;
    const float* U = (e < NEXP) ? (r_up   + (size_t)e * (DTOK * IFF)) : sh_up;
    __shared__ __bf16 lg[16][520];   // +8 pad breaks bank aliasing
    __shared__ __bf16 lu[16][520];
    const int tid = threadIdx.x;
    const int c4 = tid & 3, kk0 = tid >> 2;
    #pragma unroll
    for (int p = 0; p < 8; ++p) {
        int kk = kk0 + p * 64;
        size_t off = (size_t)(kh * 512 + kk) * IFF + j * 16 + c4 * 4;
        float4 g = *(const float4*)&G[off];
        float4 u = *(const float4*)&U[off];
        lg[c4*4+0][kk] = (__bf16)g.x; lg[c4*4+1][kk] = (__bf16)g.y;
        lg[c4*4+2][kk] = (__bf16)g.z; lg[c4*4+3][kk] = (__bf16)g.w;
        lu[c4*4+0][kk] = (__bf16)u.x; lu[c4*4+1][kk] = (__bf16)u.y;
        lu[c4*4+2][kk] = (__bf16)u.z; lu[c4*4+3][kk] = (__bf16)u.w;
    }
    __syncthreads();
    const int rr = tid >> 3;          // 0..31 (16 gate + 16 up rows)
    const int ch0 = tid & 7;
    const int cc = rr & 15;
    const bool isup = rr >= 16;
    const int r = j * 32 + (isup ? 16 : 0) + cc;
    const __bf16* src = isup ? &lu[cc][0] : &lg[cc][0];
    __bf16* dst = B1 + ((size_t)e << 20) + (size_t)r * DTOK + kh * 512;
    #pragma unroll
    for (int q = 0; q < 8; ++q) {
        int ch = ch0 + q * 8;
        *(v8bf*)&dst[ch * 8] = *(const v8bf*)&src[ch * 8];
    }
}

// B2[e][n][k] = down[k][n]. block = (kh in [0,2), nb in [0,16), e in [0,8))
__global__ __launch_bounds__(256) void build_B2t(
    const float* __restrict__ r_down, const float* __restrict__ sh_down,
    __bf16* __restrict__ B2) {
    const int kh = blockIdx.x, nb = blockIdx.y, e = blockIdx.z;
    const float* D = (e < NEXP) ? (r_down + (size_t)e * (IFF * DTOK)) : sh_down;
    __shared__ __bf16 ln[64][264];
    const int tid = threadIdx.x;
    const int c4 = tid & 15, kk0 = tid >> 4;
    #pragma unroll
    for (int p = 0; p < 16; ++p) {
        int kk = kk0 + p * 16;
        size_t off = (size_t)(kh * 256 + kk) * DTOK + nb * 64 + c4 * 4;
        float4 v = *(const float4*)&D[off];
        ln[c4*4+0][kk] = (__bf16)v.x; ln[c4*4+1][kk] = (__bf16)v.y;
        ln[c4*4+2][kk] = (__bf16)v.z; ln[c4*4+3][kk] = (__bf16)v.w;
    }
    __syncthreads();
    const int nn = tid >> 2;          // 0..63
    const int ch0 = tid & 3;
    __bf16* dst = B2 + ((size_t)e * 1024 + nb * 64 + nn) * IFF + kh * 256;
    #pragma unroll
    for (int q = 0; q < 8; ++q) {
        int ch = ch0 + q * 4;
        *(v8bf*)&dst[ch * 8] = *(const v8bf*)&ln[nn][ch * 8];
    }
}

// Deterministic atomic-free gather build (scan), COALESCED partition and fused
// init (pad slots, tail, shared identity segment, zpage). Slot order within a
// segment is arbitrary-but-deterministic (combine sums via tok_slot).
__global__ __launch_bounds__(1024) void gather_kernel(
    const int* __restrict__ top_i, const float* __restrict__ top_w,
    int* __restrict__ slot_token, float* __restrict__ slot_w,
    int* __restrict__ tok_slot, int* __restrict__ offs_out,
    __bf16* __restrict__ zpage) {
    __shared__ int h[NEXP][1024];
    __shared__ int lofs[NEXP];
    const int tid = threadIdx.x;

    int cnt[NEXP] = {0,0,0,0,0,0,0};
    int emem[32];
    float wmem[32];
    #pragma unroll
    for (int j = 0; j < 32; ++j) {
        int idx = tid + j * 1024;             // coalesced
        emem[j] = top_i[idx];
        wmem[j] = top_w[idx];
        #pragma unroll
        for (int q = 0; q < NEXP; ++q) if (emem[j] == q) cnt[q]++;
    }
    #pragma unroll
    for (int q = 0; q < NEXP; ++q) h[q][tid] = cnt[q];
    __syncthreads();
    // inclusive scan across 1024 threads, all 7 experts in parallel
    for (int off = 1; off < 1024; off <<= 1) {
        int v[NEXP];
        #pragma unroll
        for (int q = 0; q < NEXP; ++q) v[q] = (tid >= off) ? h[q][tid - off] : 0;
        __syncthreads();
        #pragma unroll
        for (int q = 0; q < NEXP; ++q) h[q][tid] += v[q];
        __syncthreads();
    }
    if (tid == 0) {
        int o = 0;
        #pragma unroll
        for (int q = 0; q < NEXP; ++q) { lofs[q] = o; o += ((h[q][1023] + 127) >> 7) << 7; }
        #pragma unroll
        for (int q = 0; q < NEXP; ++q) offs_out[q] = lofs[q];
        offs_out[NEXP] = CAP;   // expert 7 = shared segment
    }
    __syncthreads();
    int pos[NEXP];
    #pragma unroll
    for (int q = 0; q < NEXP; ++q) pos[q] = lofs[q] + h[q][tid] - cnt[q];  // exclusive base
    #pragma unroll
    for (int j = 0; j < 32; ++j) {
        int idx = tid + j * 1024;
        int t = idx >> 1;
        #pragma unroll
        for (int q = 0; q < NEXP; ++q) if (emem[j] == q) {
            slot_token[pos[q]] = t;
            slot_w[pos[q]] = wmem[j];
            tok_slot[idx] = pos[q];
            pos[q]++;
        }
    }
    // ---- fused init (disjoint writes; operands already in LDS) ----
    #pragma unroll
    for (int q = 0; q < NEXP; ++q) {
        int tot = h[q][1023];
        int seg = ((tot + 127) >> 7) << 7;
        if (tid < seg - tot) slot_token[lofs[q] + tot + tid] = -1;
    }
    {
        int tot6 = h[NEXP - 1][1023];
        int ototal = lofs[NEXP - 1] + (((tot6 + 127) >> 7) << 7);
        for (int j = ototal + tid; j < CAP; j += 1024) slot_token[j] = -1;
    }
    for (int j = tid; j < TTOK; j += 1024) {
        slot_token[CAP + j] = j;
        slot_w[CAP + j] = 1.f;
    }
    // zero page: 2048 bf16 so pad rows can use uniform base+ks addressing
    zpage[tid] = (__bf16)0.f;
    zpage[1024 + tid] = (__bf16)0.f;
}

// ---------------- MFMA GEMM (128x128 tile, BK=64, 4 waves, T2 swizzle, T1 XCD swizzle) ----
// UNR per-instantiation (R11/R12/R13 attribution matrix):
//   KDIM=1024 EPI=0: UNR=true  (166->126us, MfmaUtil 27->35.5%)  [R11 measured]
//   KDIM=512  EPI=2: UNR=true  <- THIS ROUND's single variable
//   KDIM=512  EPI=3: UNR=false (R11's pair-flip regressed ~60us; theory: EPI=3's
//                     heavy epilogue is the regalloc victim of the unrolled body)
// EPI: 0 = SwiGLU pair -> Hout bf16 [M, 512]
//      1 = plain fp32 write to out
//      2 = weighted write:  yr[m][c] = slot_w[m] * acc (skip pad rows), YT = bf16
//      3 = fused combine:   out[m][c] = acc + yr[s0][c] + yr[s1][c]
//      4 = atomicAdd fallback (small-ws path)
template<int KDIM, int EPI, bool GATHER, bool UNR, typename YT>
__global__ __launch_bounds__(256) void gemm_kernel(
    const __bf16* __restrict__ A, const __bf16* __restrict__ Bmat,
    const int* __restrict__ offs, const int* __restrict__ slot_token,
    const float* __restrict__ slot_w, const int* __restrict__ tok_slot,
    YT* __restrict__ yr,
    __bf16* __restrict__ Hout, float* __restrict__ out,
    const __bf16* __restrict__ zpage) {
    // T1: XCD-aware decode. HW: block b -> XCD b%8; j-th block on XCD x covers
    // logical L = x*cpx + j  (cpx = nwg/8, all our grids divisible by 8).
    const int nwg = gridDim.x;
    const int cpx = nwg >> 3;
    const int bid = blockIdx.x;
    const int L = (bid & 7) * cpx + (bid >> 3);
    const int tileN = L & 7;          // 8 N-tiles of 128 (N = 1024)
    const int tileM = L >> 3;
    const int tid = threadIdx.x, lane = tid & 63, wid = tid >> 6;
    const int wm = wid >> 1, wn = wid & 1;

    __shared__ __bf16 As[128 * 64];
    __shared__ __bf16 Bs[128 * 64];

    // per-tile expert B selection (segments 128-aligned; offs[7]=CAP = shared)
    const __bf16* Bp = Bmat;
    if (offs) {
        int m0 = tileM * 128, e = 0;
        #pragma unroll
        for (int i = 1; i < NEXP + 1; ++i) if (m0 >= offs[i]) e = i;
        Bp = Bmat + (size_t)e * (1024 * KDIM);
    }

    f32x4 acc[4][4] = {};

    // staging: wave stages 4 chunks of 8 rows; LDS dest linear (base + lane*16B).
    // T2: global source block q^row; read side XORs back (involution).
    const int lrow = lane >> 3;
    const int lk = (((lane & 7) ^ lrow) * 8);
    const __bf16* abase[4];
    const __bf16* bbase[4];
    #pragma unroll
    for (int i = 0; i < 4; ++i) {
        int ra = tileM * 128 + (wid * 4 + i) * 8 + lrow;
        if (GATHER) {
            int tok = slot_token[ra];
            abase[i] = (tok >= 0 ? A + (size_t)tok * KDIM : zpage) + lk;
        } else { abase[i] = A + (size_t)ra * KDIM + lk; }
        int rb_ = tileN * 128 + (wid * 4 + i) * 8 + lrow;
        bbase[i] = Bp + (size_t)rb_ * KDIM + lk;
    }

    const int swz = (lane & 7) << 3;

#define KSTEP(KS)                                                              \
    do {                                                                       \
        _Pragma("unroll")                                                      \
        for (int i = 0; i < 4; ++i) {                                          \
            __builtin_amdgcn_global_load_lds((const AS1 void*)(abase[i] + (KS)),\
                (AS3 void*)&As[(wid * 4 + i) * 512 + lane * 8], 16, 0, 0);     \
        }                                                                      \
        _Pragma("unroll")                                                      \
        for (int i = 0; i < 4; ++i) {                                          \
            __builtin_amdgcn_global_load_lds((const AS1 void*)(bbase[i] + (KS)),\
                (AS3 void*)&Bs[(wid * 4 + i) * 512 + lane * 8], 16, 0, 0);     \
        }                                                                      \
        __syncthreads();                                                       \
        _Pragma("unroll")                                                      \
        for (int kk = 0; kk < 64; kk += 32) {                                  \
            v8bf a[4], b[4];                                                   \
            int kof = (kk + ((lane >> 4) << 3)) ^ swz;                         \
            int ar = wm * 64 + (lane & 15);                                    \
            int br = wn * 64 + (lane & 15);                                    \
            _Pragma("unroll")                                                  \
            for (int mi = 0; mi < 4; ++mi)                                     \
                a[mi] = *reinterpret_cast<const v8bf*>(&As[(ar + mi * 16) * 64 + kof]); \
            _Pragma("unroll")                                                  \
            for (int ni = 0; ni < 4; ++ni)                                     \
                b[ni] = *reinterpret_cast<const v8bf*>(&Bs[(br + ni * 16) * 64 + kof]); \
            _Pragma("unroll")                                                  \
            for (int mi = 0; mi < 4; ++mi)                                     \
                _Pragma("unroll")                                              \
                for (int ni = 0; ni < 4; ++ni)                                 \
                    acc[mi][ni] = __builtin_amdgcn_mfma_f32_16x16x32_bf16(     \
                        a[mi], b[ni], acc[mi][ni], 0, 0, 0);                   \
        }                                                                      \
        __syncthreads();                                                       \
    } while (0)

    if constexpr (UNR) {
        #pragma unroll
        for (int ks = 0; ks < KDIM; ks += 64) KSTEP(ks);
    } else {
        for (int ks = 0; ks < KDIM; ks += 64) KSTEP(ks);
    }
#undef KSTEP

    // epilogue: C/D layout col = lane&15, row = (lane>>4)*4 + reg
    const int mbase = tileM * 128 + wm * 64;
    const int nbase = tileN * 128 + wn * 64;
    const int rowoff = (lane >> 4) * 4;
    const int col = lane & 15;

    if constexpr (EPI == 0) {
        #pragma unroll
        for (int mi = 0; mi < 4; ++mi)
            #pragma unroll
            for (int pi = 0; pi < 2; ++pi) {
                int ni = pi * 2;
                int hcol = (((nbase + ni * 16) >> 5) << 4) + col;
                #pragma unroll
                for (int j = 0; j < 4; ++j) {
                    int m = mbase + mi * 16 + rowoff + j;
                    float g = acc[mi][ni][j];
                    float u = acc[mi][ni + 1][j];
                    float h = (g / (1.f + __expf(-g))) * u;   // silu(g)*u
                    Hout[(size_t)m * IFF + hcol] = (__bf16)h;
                }
            }
    } else if constexpr (EPI == 1) {
        #pragma unroll
        for (int mi = 0; mi < 4; ++mi)
            #pragma unroll
            for (int j = 0; j < 4; ++j) {
                int m = mbase + mi * 16 + rowoff + j;
                #pragma unroll
                for (int ni = 0; ni < 4; ++ni)
                    out[(size_t)m * DTOK + nbase + ni * 16 + col] = acc[mi][ni][j];
            }
    } else if constexpr (EPI == 2) {
        #pragma unroll
        for (int mi = 0; mi < 4; ++mi)
            #pragma unroll
            for (int j = 0; j < 4; ++j) {
                int m = mbase + mi * 16 + rowoff + j;
                if (slot_token[m] < 0) continue;
                float wgt = slot_w[m];
                #pragma unroll
                for (int ni = 0; ni < 4; ++ni)
                    yr[(size_t)m * DTOK + nbase + ni * 16 + col] = (YT)(wgt * acc[mi][ni][j]);
            }
    } else if constexpr (EPI == 3) {
        #pragma unroll
        for (int mi = 0; mi < 4; ++mi)
            #pragma unroll
            for (int j = 0; j < 4; ++j) {
                int m = mbase + mi * 16 + rowoff + j;
                int s0 = tok_slot[2 * m], s1 = tok_slot[2 * m + 1];
                const YT* y0 = yr + (size_t)s0 * DTOK;
                const YT* y1 = yr + (size_t)s1 * DTOK;
                #pragma unroll
                for (int ni = 0; ni < 4; ++ni) {
                    int c = nbase + ni * 16 + col;
                    out[(size_t)m * DTOK + c] = acc[mi][ni][j] + (float)y0[c] + (float)y1[c];
                }
            }
    } else {  // EPI == 4: atomic fallback
        #pragma unroll
        for (int mi = 0; mi < 4; ++mi)
            #pragma unroll
            for (int j = 0; j < 4; ++j) {
                int m = mbase + mi * 16 + rowoff + j;
                int tok = slot_token[m];
                if (tok < 0) continue;
                float wgt = slot_w[m];
                #pragma unroll
                for (int ni = 0; ni < 4; ++ni)
                    atomicAdd(out + (size_t)tok * DTOK + nbase + ni * 16 + col, wgt * acc[mi][ni][j]);
            }
    }
}

// ---------------- launcher ----------------
extern "C" void kernel_launch(void* const* d_in, const int* in_sizes, int n_in,
                              void* d_out, int out_size, void* d_ws, size_t ws_size,
                              hipStream_t stream) {
    const float* x       = (const float*)d_in[0];
    const float* sh_gate = (const float*)d_in[1];
    const float* sh_up   = (const float*)d_in[2];
    const float* sh_down = (const float*)d_in[3];
    const float* r_gate  = (const float*)d_in[4];
    const float* r_up    = (const float*)d_in[5];
    const float* r_down  = (const float*)d_in[6];
    const float* w_r     = (const float*)d_in[7];
    const float* b_r     = (const float*)d_in[8];
    const float* rb      = (const float*)d_in[9];
    float* out = (float*)d_out;

    char* w = (char*)d_ws;
    __bf16* xb = (__bf16*)w;          w += (size_t)TTOK * DTOK * 2;            // 33.55 MB
    __bf16* B1 = (__bf16*)w;          w += (size_t)8 * 1024 * 1024 * 2;        // 16.78 MB
    __bf16* B2 = (__bf16*)w;          w += (size_t)8 * 1024 * 512 * 2;         //  8.39 MB
    __bf16* H  = (__bf16*)w;          w += (size_t)CAPX * IFF * 2;             // 51.25 MB (routed | shared)
    int*    top_i = (int*)w;          w += (size_t)TTOK * 2 * 4;
    float*  top_w = (float*)w;        w += (size_t)TTOK * 2 * 4;
    int*    slot_token = (int*)w;     w += (size_t)CAPX * 4;
    float*  slot_w = (float*)w;       w += (size_t)CAPX * 4;
    int*    tok_slot = (int*)w;       w += (size_t)TTOK * 2 * 4;
    int*    offs = (int*)w;           w += 256;
    __bf16* zpage = (__bf16*)w;       w += 4096;   // 2048 bf16 zeros
    void*   Yr = (void*)w;
    size_t used = (size_t)(w - (char*)d_ws);
    size_t rem = (ws_size > used) ? (ws_size - used) : 0;
    bool have_yr = rem >= (size_t)CAP * DTOK * 2;   // bf16 Yr = 68.9 MB

    router_cast_kernel<<<TTOK / 4, 256, 0, stream>>>(
        (const float4*)x, w_r, b_r, rb, xb, top_i, top_w);
    build_B1t<<<dim3(2, 32, 8), 256, 0, stream>>>(r_gate, r_up, sh_gate, sh_up, B1);
    build_B2t<<<dim3(2, 16, 8), 256, 0, stream>>>(r_down, sh_down, B2);
    gather_kernel<<<1, 1024, 0, stream>>>(top_i, top_w, slot_token, slot_w, tok_slot, offs, zpage);

    dim3 blk(256);
    // GEMM1 merged (routed + shared): gathered A rows, per-segment expert B, -> H
    // UNR=true (measured R11/R12: 126us, MfmaUtil 35.5%)
    gemm_kernel<DTOK, 0, true, true, __bf16><<<(CAPX / 128) * 8, blk, 0, stream>>>(
        xb, B1, offs, slot_token, nullptr, nullptr, nullptr, H, nullptr, zpage);

    if (have_yr) {
        __bf16* yr = (__bf16*)Yr;
        // GEMM2 routed: H[0..CAP) x down^T -> yr = w * y (bf16). UNR=true (R13 single variable)
        gemm_kernel<IFF, 2, false, true, __bf16><<<(CAP / 128) * 8, blk, 0, stream>>>(
            H, B2, offs, slot_token, slot_w, nullptr, yr, nullptr, nullptr, zpage);
        // GEMM2 shared+combine: H[CAP..) x down7^T; out = acc + yr[s0] + yr[s1]. UNR=false
        gemm_kernel<IFF, 3, false, false, __bf16><<<(TTOK / 128) * 8, blk, 0, stream>>>(
            H + (size_t)CAP * IFF, B2 + (size_t)NEXP * 1024 * 512,
            nullptr, nullptr, nullptr, tok_slot, yr, nullptr, out, zpage);
    } else {
        // fallback: shared plain write, routed atomic accumulate
        gemm_kernel<IFF, 1, false, false, __bf16><<<(TTOK / 128) * 8, blk, 0, stream>>>(
            H + (size_t)CAP * IFF, B2 + (size_t)NEXP * 1024 * 512,
            nullptr, nullptr, nullptr, nullptr, nullptr, nullptr, out, zpage);
        gemm_kernel<IFF, 4, false, false, __bf16><<<(CAP / 128) * 8, blk, 0, stream>>>(
            H, B2, offs, slot_token, slot_w, nullptr, nullptr, nullptr, out, zpage);
    }
}

// Round 14
// 357.551 us; speedup vs baseline: 1.0076x; 1.0076x over previous
//
#include <hip/hip_runtime.h>
#include <hip/hip_bf16.h>
#include <cstdint>
#include <cstddef>

// ---------------- problem constants ----------------
#define DTOK 1024      // embed dim
#define IFF  512       // ffn intermediate
#define NEXP 7         // routed experts
#define TTOK 16384     // B*S tokens
#define CAP  (2*TTOK + NEXP*128)   // padded routed slot capacity = 33664 (263 tiles of 128)
#define CAPX (CAP + TTOK)          // + shared segment (expert 7, identity) = 50048

typedef __bf16 v8bf  __attribute__((ext_vector_type(8)));
typedef float  f32x4 __attribute__((ext_vector_type(4)));

#define AS1 __attribute__((address_space(1)))
#define AS3 __attribute__((address_space(3)))

// ---------------- small prep kernels ----------------

// Router fused with x->bf16 cast. One wave per token; logits in full fp32
// (bf16 x would flip near-tie top-k picks). Reads x as float4 (coalesced),
// writes xb as 4x bf16 per lane (8B, coalesced).
__global__ __launch_bounds__(256) void router_cast_kernel(
    const float4* __restrict__ x4, const float* __restrict__ w_r,
    const float* __restrict__ b_r, const float* __restrict__ rb,
    __bf16* __restrict__ xb, int* __restrict__ top_i, float* __restrict__ top_w) {
    typedef __bf16 v4bf __attribute__((ext_vector_type(4)));
    const int wid = threadIdx.x >> 6, lane = threadIdx.x & 63;
    const int t = blockIdx.x * 4 + wid;
    float acc[NEXP] = {0.f,0.f,0.f,0.f,0.f,0.f,0.f};
    #pragma unroll
    for (int it = 0; it < 4; ++it) {
        const int c = it * 64 + lane;              // float4 index within row
        float4 xv = x4[(size_t)t * 256 + c];
        v4bf o; o[0] = (__bf16)xv.x; o[1] = (__bf16)xv.y;
                o[2] = (__bf16)xv.z; o[3] = (__bf16)xv.w;
        *reinterpret_cast<v4bf*>(xb + (size_t)t * DTOK + c * 4) = o;
        const float* wr = w_r + (size_t)c * 4 * NEXP;   // w_r is [1024][7], 28KB total (cached)
        #pragma unroll
        for (int e = 0; e < NEXP; ++e)
            acc[e] += xv.x * wr[e] + xv.y * wr[NEXP + e]
                    + xv.z * wr[2 * NEXP + e] + xv.w * wr[3 * NEXP + e];
    }
    #pragma unroll
    for (int e = 0; e < NEXP; ++e)
        #pragma unroll
        for (int off = 32; off; off >>= 1) acc[e] += __shfl_xor(acc[e], off);
    if (lane == 0) {
        float p[NEXP];
        #pragma unroll
        for (int e = 0; e < NEXP; ++e) p[e] = 1.f / (1.f + expf(-(acc[e] + b_r[e] + rb[e])));
        int i0 = 0;
        #pragma unroll
        for (int e = 1; e < NEXP; ++e) if (p[e] > p[i0]) i0 = e;   // ties -> lowest idx
        int i1 = -1;
        #pragma unroll
        for (int e = 0; e < NEXP; ++e) if (e != i0 && (i1 < 0 || p[e] > p[i1])) i1 = e;
        float s = p[i0] + p[i1];
        top_i[2 * t] = i0; top_i[2 * t + 1] = i1;
        top_w[2 * t] = p[i0] / s; top_w[2 * t + 1] = p[i1] / s;
    }
}

// B1[e][r][k] = W[k][c], c=(r>>5)*16+(r&15), gate if (r&31)<16 else up.
// Coalesced via LDS transpose. block = (kh in [0,2), j in [0,32), e in [0,8))
__global__ __launch_bounds__(256) void build_B1t(
    const float* __restrict__ r_gate, const float* __restrict__ r_up,
    const float* __restrict__ sh_gate, const float* __restrict__ sh_up,
    __bf16* __restrict__ B1) {
    const int kh = blockIdx.x, j = blockIdx.y, e = blockIdx.z;
    const float* G = (e < NEXP) ? (r_gate + (size_t)e * (DTOK * IFF)) : sh_gate;
    const float* U = (e < NEXP) ? (r_up   + (size_t)e * (DTOK * IFF)) : sh_up;
    __shared__ __bf16 lg[16][520];   // +8 pad breaks bank aliasing
    __shared__ __bf16 lu[16][520];
    const int tid = threadIdx.x;
    const int c4 = tid & 3, kk0 = tid >> 2;
    #pragma unroll
    for (int p = 0; p < 8; ++p) {
        int kk = kk0 + p * 64;
        size_t off = (size_t)(kh * 512 + kk) * IFF + j * 16 + c4 * 4;
        float4 g = *(const float4*)&G[off];
        float4 u = *(const float4*)&U[off];
        lg[c4*4+0][kk] = (__bf16)g.x; lg[c4*4+1][kk] = (__bf16)g.y;
        lg[c4*4+2][kk] = (__bf16)g.z; lg[c4*4+3][kk] = (__bf16)g.w;
        lu[c4*4+0][kk] = (__bf16)u.x; lu[c4*4+1][kk] = (__bf16)u.y;
        lu[c4*4+2][kk] = (__bf16)u.z; lu[c4*4+3][kk] = (__bf16)u.w;
    }
    __syncthreads();
    const int rr = tid >> 3;          // 0..31 (16 gate + 16 up rows)
    const int ch0 = tid & 7;
    const int cc = rr & 15;
    const bool isup = rr >= 16;
    const int r = j * 32 + (isup ? 16 : 0) + cc;
    const __bf16* src = isup ? &lu[cc][0] : &lg[cc][0];
    __bf16* dst = B1 + ((size_t)e << 20) + (size_t)r * DTOK + kh * 512;
    #pragma unroll
    for (int q = 0; q < 8; ++q) {
        int ch = ch0 + q * 8;
        *(v8bf*)&dst[ch * 8] = *(const v8bf*)&src[ch * 8];
    }
}

// B2[e][n][k] = down[k][n]. block = (kh in [0,2), nb in [0,16), e in [0,8))
__global__ __launch_bounds__(256) void build_B2t(
    const float* __restrict__ r_down, const float* __restrict__ sh_down,
    __bf16* __restrict__ B2) {
    const int kh = blockIdx.x, nb = blockIdx.y, e = blockIdx.z;
    const float* D = (e < NEXP) ? (r_down + (size_t)e * (IFF * DTOK)) : sh_down;
    __shared__ __bf16 ln[64][264];
    const int tid = threadIdx.x;
    const int c4 = tid & 15, kk0 = tid >> 4;
    #pragma unroll
    for (int p = 0; p < 16; ++p) {
        int kk = kk0 + p * 16;
        size_t off = (size_t)(kh * 256 + kk) * DTOK + nb * 64 + c4 * 4;
        float4 v = *(const float4*)&D[off];
        ln[c4*4+0][kk] = (__bf16)v.x; ln[c4*4+1][kk] = (__bf16)v.y;
        ln[c4*4+2][kk] = (__bf16)v.z; ln[c4*4+3][kk] = (__bf16)v.w;
    }
    __syncthreads();
    const int nn = tid >> 2;          // 0..63
    const int ch0 = tid & 3;
    __bf16* dst = B2 + ((size_t)e * 1024 + nb * 64 + nn) * IFF + kh * 256;
    #pragma unroll
    for (int q = 0; q < 8; ++q) {
        int ch = ch0 + q * 4;
        *(v8bf*)&dst[ch * 8] = *(const v8bf*)&ln[nn][ch * 8];
    }
}

// Deterministic atomic-free gather build (scan), COALESCED partition and fused
// init (pad slots, tail, shared identity segment, zpage). Slot order within a
// segment is arbitrary-but-deterministic (combine sums via tok_slot).
__global__ __launch_bounds__(1024) void gather_kernel(
    const int* __restrict__ top_i, const float* __restrict__ top_w,
    int* __restrict__ slot_token, float* __restrict__ slot_w,
    int* __restrict__ tok_slot, int* __restrict__ offs_out,
    __bf16* __restrict__ zpage) {
    __shared__ int h[NEXP][1024];
    __shared__ int lofs[NEXP];
    const int tid = threadIdx.x;

    int cnt[NEXP] = {0,0,0,0,0,0,0};
    int emem[32];
    float wmem[32];
    #pragma unroll
    for (int j = 0; j < 32; ++j) {
        int idx = tid + j * 1024;             // coalesced
        emem[j] = top_i[idx];
        wmem[j] = top_w[idx];
        #pragma unroll
        for (int q = 0; q < NEXP; ++q) if (emem[j] == q) cnt[q]++;
    }
    #pragma unroll
    for (int q = 0; q < NEXP; ++q) h[q][tid] = cnt[q];
    __syncthreads();
    // inclusive scan across 1024 threads, all 7 experts in parallel
    for (int off = 1; off < 1024; off <<= 1) {
        int v[NEXP];
        #pragma unroll
        for (int q = 0; q < NEXP; ++q) v[q] = (tid >= off) ? h[q][tid - off] : 0;
        __syncthreads();
        #pragma unroll
        for (int q = 0; q < NEXP; ++q) h[q][tid] += v[q];
        __syncthreads();
    }
    if (tid == 0) {
        int o = 0;
        #pragma unroll
        for (int q = 0; q < NEXP; ++q) { lofs[q] = o; o += ((h[q][1023] + 127) >> 7) << 7; }
        #pragma unroll
        for (int q = 0; q < NEXP; ++q) offs_out[q] = lofs[q];
        offs_out[NEXP] = CAP;   // expert 7 = shared segment
    }
    __syncthreads();
    int pos[NEXP];
    #pragma unroll
    for (int q = 0; q < NEXP; ++q) pos[q] = lofs[q] + h[q][tid] - cnt[q];  // exclusive base
    #pragma unroll
    for (int j = 0; j < 32; ++j) {
        int idx = tid + j * 1024;
        int t = idx >> 1;
        #pragma unroll
        for (int q = 0; q < NEXP; ++q) if (emem[j] == q) {
            slot_token[pos[q]] = t;
            slot_w[pos[q]] = wmem[j];
            tok_slot[idx] = pos[q];
            pos[q]++;
        }
    }
    // ---- fused init (disjoint writes; operands already in LDS) ----
    #pragma unroll
    for (int q = 0; q < NEXP; ++q) {
        int tot = h[q][1023];
        int seg = ((tot + 127) >> 7) << 7;
        if (tid < seg - tot) slot_token[lofs[q] + tot + tid] = -1;
    }
    {
        int tot6 = h[NEXP - 1][1023];
        int ototal = lofs[NEXP - 1] + (((tot6 + 127) >> 7) << 7);
        for (int j = ototal + tid; j < CAP; j += 1024) slot_token[j] = -1;
    }
    for (int j = tid; j < TTOK; j += 1024) {
        slot_token[CAP + j] = j;
        slot_w[CAP + j] = 1.f;
    }
    // zero page: 2048 bf16 so pad rows can use uniform base+ks addressing
    zpage[tid] = (__bf16)0.f;
    zpage[1024 + tid] = (__bf16)0.f;
}

// ---------------- MFMA GEMM (128x128 tile, BK=64, 4 waves, T2 swizzle, T1 XCD swizzle) ----
// UNR per-instantiation -- FINAL attribution matrix (R10..R13 measured):
//   KDIM=1024 EPI=0: UNR=true  (166->126us, MfmaUtil 27->35.5%: staging-addr
//                     VALU eliminated, ks folds into load imm offsets)
//   KDIM=512  EPI=2: UNR=false (R13 A/B: unroll = +2.6us, noise-neutral)
//   KDIM=512  EPI=3: UNR=false (R11 pair-flip: ~-60us; heavy combine epilogue
//                     is the regalloc victim of the 8x-unrolled body)
// EPI: 0 = SwiGLU pair -> Hout bf16 [M, 512]
//      1 = plain fp32 write to out
//      2 = weighted write:  yr[m][c] = slot_w[m] * acc (skip pad rows), YT = bf16
//      3 = fused combine:   out[m][c] = acc + yr[s0][c] + yr[s1][c]
//      4 = atomicAdd fallback (small-ws path)
template<int KDIM, int EPI, bool GATHER, bool UNR, typename YT>
__global__ __launch_bounds__(256) void gemm_kernel(
    const __bf16* __restrict__ A, const __bf16* __restrict__ Bmat,
    const int* __restrict__ offs, const int* __restrict__ slot_token,
    const float* __restrict__ slot_w, const int* __restrict__ tok_slot,
    YT* __restrict__ yr,
    __bf16* __restrict__ Hout, float* __restrict__ out,
    const __bf16* __restrict__ zpage) {
    // T1: XCD-aware decode. HW: block b -> XCD b%8; j-th block on XCD x covers
    // logical L = x*cpx + j  (cpx = nwg/8, all our grids divisible by 8).
    const int nwg = gridDim.x;
    const int cpx = nwg >> 3;
    const int bid = blockIdx.x;
    const int L = (bid & 7) * cpx + (bid >> 3);
    const int tileN = L & 7;          // 8 N-tiles of 128 (N = 1024)
    const int tileM = L >> 3;
    const int tid = threadIdx.x, lane = tid & 63, wid = tid >> 6;
    const int wm = wid >> 1, wn = wid & 1;

    __shared__ __bf16 As[128 * 64];
    __shared__ __bf16 Bs[128 * 64];

    // per-tile expert B selection (segments 128-aligned; offs[7]=CAP = shared)
    const __bf16* Bp = Bmat;
    if (offs) {
        int m0 = tileM * 128, e = 0;
        #pragma unroll
        for (int i = 1; i < NEXP + 1; ++i) if (m0 >= offs[i]) e = i;
        Bp = Bmat + (size_t)e * (1024 * KDIM);
    }

    f32x4 acc[4][4] = {};

    // staging: wave stages 4 chunks of 8 rows; LDS dest linear (base + lane*16B).
    // T2: global source block q^row; read side XORs back (involution).
    const int lrow = lane >> 3;
    const int lk = (((lane & 7) ^ lrow) * 8);
    const __bf16* abase[4];
    const __bf16* bbase[4];
    #pragma unroll
    for (int i = 0; i < 4; ++i) {
        int ra = tileM * 128 + (wid * 4 + i) * 8 + lrow;
        if (GATHER) {
            int tok = slot_token[ra];
            abase[i] = (tok >= 0 ? A + (size_t)tok * KDIM : zpage) + lk;
        } else { abase[i] = A + (size_t)ra * KDIM + lk; }
        int rb_ = tileN * 128 + (wid * 4 + i) * 8 + lrow;
        bbase[i] = Bp + (size_t)rb_ * KDIM + lk;
    }

    const int swz = (lane & 7) << 3;

#define KSTEP(KS)                                                              \
    do {                                                                       \
        _Pragma("unroll")                                                      \
        for (int i = 0; i < 4; ++i) {                                          \
            __builtin_amdgcn_global_load_lds((const AS1 void*)(abase[i] + (KS)),\
                (AS3 void*)&As[(wid * 4 + i) * 512 + lane * 8], 16, 0, 0);     \
        }                                                                      \
        _Pragma("unroll")                                                      \
        for (int i = 0; i < 4; ++i) {                                          \
            __builtin_amdgcn_global_load_lds((const AS1 void*)(bbase[i] + (KS)),\
                (AS3 void*)&Bs[(wid * 4 + i) * 512 + lane * 8], 16, 0, 0);     \
        }                                                                      \
        __syncthreads();                                                       \
        _Pragma("unroll")                                                      \
        for (int kk = 0; kk < 64; kk += 32) {                                  \
            v8bf a[4], b[4];                                                   \
            int kof = (kk + ((lane >> 4) << 3)) ^ swz;                         \
            int ar = wm * 64 + (lane & 15);                                    \
            int br = wn * 64 + (lane & 15);                                    \
            _Pragma("unroll")                                                  \
            for (int mi = 0; mi < 4; ++mi)                                     \
                a[mi] = *reinterpret_cast<const v8bf*>(&As[(ar + mi * 16) * 64 + kof]); \
            _Pragma("unroll")                                                  \
            for (int ni = 0; ni < 4; ++ni)                                     \
                b[ni] = *reinterpret_cast<const v8bf*>(&Bs[(br + ni * 16) * 64 + kof]); \
            _Pragma("unroll")                                                  \
            for (int mi = 0; mi < 4; ++mi)                                     \
                _Pragma("unroll")                                              \
                for (int ni = 0; ni < 4; ++ni)                                 \
                    acc[mi][ni] = __builtin_amdgcn_mfma_f32_16x16x32_bf16(     \
                        a[mi], b[ni], acc[mi][ni], 0, 0, 0);                   \
        }                                                                      \
        __syncthreads();                                                       \
    } while (0)

    if constexpr (UNR) {
        #pragma unroll
        for (int ks = 0; ks < KDIM; ks += 64) KSTEP(ks);
    } else {
        for (int ks = 0; ks < KDIM; ks += 64) KSTEP(ks);
    }
#undef KSTEP

    // epilogue: C/D layout col = lane&15, row = (lane>>4)*4 + reg
    const int mbase = tileM * 128 + wm * 64;
    const int nbase = tileN * 128 + wn * 64;
    const int rowoff = (lane >> 4) * 4;
    const int col = lane & 15;

    if constexpr (EPI == 0) {
        #pragma unroll
        for (int mi = 0; mi < 4; ++mi)
            #pragma unroll
            for (int pi = 0; pi < 2; ++pi) {
                int ni = pi * 2;
                int hcol = (((nbase + ni * 16) >> 5) << 4) + col;
                #pragma unroll
                for (int j = 0; j < 4; ++j) {
                    int m = mbase + mi * 16 + rowoff + j;
                    float g = acc[mi][ni][j];
                    float u = acc[mi][ni + 1][j];
                    float h = (g / (1.f + __expf(-g))) * u;   // silu(g)*u
                    Hout[(size_t)m * IFF + hcol] = (__bf16)h;
                }
            }
    } else if constexpr (EPI == 1) {
        #pragma unroll
        for (int mi = 0; mi < 4; ++mi)
            #pragma unroll
            for (int j = 0; j < 4; ++j) {
                int m = mbase + mi * 16 + rowoff + j;
                #pragma unroll
                for (int ni = 0; ni < 4; ++ni)
                    out[(size_t)m * DTOK + nbase + ni * 16 + col] = acc[mi][ni][j];
            }
    } else if constexpr (EPI == 2) {
        #pragma unroll
        for (int mi = 0; mi < 4; ++mi)
            #pragma unroll
            for (int j = 0; j < 4; ++j) {
                int m = mbase + mi * 16 + rowoff + j;
                if (slot_token[m] < 0) continue;
                float wgt = slot_w[m];
                #pragma unroll
                for (int ni = 0; ni < 4; ++ni)
                    yr[(size_t)m * DTOK + nbase + ni * 16 + col] = (YT)(wgt * acc[mi][ni][j]);
            }
    } else if constexpr (EPI == 3) {
        #pragma unroll
        for (int mi = 0; mi < 4; ++mi)
            #pragma unroll
            for (int j = 0; j < 4; ++j) {
                int m = mbase + mi * 16 + rowoff + j;
                int s0 = tok_slot[2 * m], s1 = tok_slot[2 * m + 1];
                const YT* y0 = yr + (size_t)s0 * DTOK;
                const YT* y1 = yr + (size_t)s1 * DTOK;
                #pragma unroll
                for (int ni = 0; ni < 4; ++ni) {
                    int c = nbase + ni * 16 + col;
                    out[(size_t)m * DTOK + c] = acc[mi][ni][j] + (float)y0[c] + (float)y1[c];
                }
            }
    } else {  // EPI == 4: atomic fallback
        #pragma unroll
        for (int mi = 0; mi < 4; ++mi)
            #pragma unroll
            for (int j = 0; j < 4; ++j) {
                int m = mbase + mi * 16 + rowoff + j;
                int tok = slot_token[m];
                if (tok < 0) continue;
                float wgt = slot_w[m];
                #pragma unroll
                for (int ni = 0; ni < 4; ++ni)
                    atomicAdd(out + (size_t)tok * DTOK + nbase + ni * 16 + col, wgt * acc[mi][ni][j]);
            }
    }
}

// ---------------- launcher ----------------
extern "C" void kernel_launch(void* const* d_in, const int* in_sizes, int n_in,
                              void* d_out, int out_size, void* d_ws, size_t ws_size,
                              hipStream_t stream) {
    const float* x       = (const float*)d_in[0];
    const float* sh_gate = (const float*)d_in[1];
    const float* sh_up   = (const float*)d_in[2];
    const float* sh_down = (const float*)d_in[3];
    const float* r_gate  = (const float*)d_in[4];
    const float* r_up    = (const float*)d_in[5];
    const float* r_down  = (const float*)d_in[6];
    const float* w_r     = (const float*)d_in[7];
    const float* b_r     = (const float*)d_in[8];
    const float* rb      = (const float*)d_in[9];
    float* out = (float*)d_out;

    char* w = (char*)d_ws;
    __bf16* xb = (__bf16*)w;          w += (size_t)TTOK * DTOK * 2;            // 33.55 MB
    __bf16* B1 = (__bf16*)w;          w += (size_t)8 * 1024 * 1024 * 2;        // 16.78 MB
    __bf16* B2 = (__bf16*)w;          w += (size_t)8 * 1024 * 512 * 2;         //  8.39 MB
    __bf16* H  = (__bf16*)w;          w += (size_t)CAPX * IFF * 2;             // 51.25 MB (routed | shared)
    int*    top_i = (int*)w;          w += (size_t)TTOK * 2 * 4;
    float*  top_w = (float*)w;        w += (size_t)TTOK * 2 * 4;
    int*    slot_token = (int*)w;     w += (size_t)CAPX * 4;
    float*  slot_w = (float*)w;       w += (size_t)CAPX * 4;
    int*    tok_slot = (int*)w;       w += (size_t)TTOK * 2 * 4;
    int*    offs = (int*)w;           w += 256;
    __bf16* zpage = (__bf16*)w;       w += 4096;   // 2048 bf16 zeros
    void*   Yr = (void*)w;
    size_t used = (size_t)(w - (char*)d_ws);
    size_t rem = (ws_size > used) ? (ws_size - used) : 0;
    bool have_yr = rem >= (size_t)CAP * DTOK * 2;   // bf16 Yr = 68.9 MB

    router_cast_kernel<<<TTOK / 4, 256, 0, stream>>>(
        (const float4*)x, w_r, b_r, rb, xb, top_i, top_w);
    build_B1t<<<dim3(2, 32, 8), 256, 0, stream>>>(r_gate, r_up, sh_gate, sh_up, B1);
    build_B2t<<<dim3(2, 16, 8), 256, 0, stream>>>(r_down, sh_down, B2);
    gather_kernel<<<1, 1024, 0, stream>>>(top_i, top_w, slot_token, slot_w, tok_slot, offs, zpage);

    dim3 blk(256);
    // GEMM1 merged (routed + shared): gathered A rows, per-segment expert B, -> H
    // UNR=true (measured R11/R12: 126us, MfmaUtil 35.5%)
    gemm_kernel<DTOK, 0, true, true, __bf16><<<(CAPX / 128) * 8, blk, 0, stream>>>(
        xb, B1, offs, slot_token, nullptr, nullptr, nullptr, H, nullptr, zpage);

    if (have_yr) {
        __bf16* yr = (__bf16*)Yr;
        // GEMM2 routed: H[0..CAP) x down^T -> yr = w * y (bf16). UNR=false (R12/R13 best)
        gemm_kernel<IFF, 2, false, false, __bf16><<<(CAP / 128) * 8, blk, 0, stream>>>(
            H, B2, offs, slot_token, slot_w, nullptr, yr, nullptr, nullptr, zpage);
        // GEMM2 shared+combine: H[CAP..) x down7^T; out = acc + yr[s0] + yr[s1]. UNR=false
        gemm_kernel<IFF, 3, false, false, __bf16><<<(TTOK / 128) * 8, blk, 0, stream>>>(
            H + (size_t)CAP * IFF, B2 + (size_t)NEXP * 1024 * 512,
            nullptr, nullptr, nullptr, tok_slot, yr, nullptr, out, zpage);
    } else {
        // fallback: shared plain write, routed atomic accumulate
        gemm_kernel<IFF, 1, false, false, __bf16><<<(TTOK / 128) * 8, blk, 0, stream>>>(
            H + (size_t)CAP * IFF, B2 + (size_t)NEXP * 1024 * 512,
            nullptr, nullptr, nullptr, nullptr, nullptr, nullptr, out, zpage);
        gemm_kernel<IFF, 4, false, false, __bf16><<<(CAP / 128) * 8, blk, 0, stream>>>(
            H, B2, offs, slot_token, slot_w, nullptr, nullptr, nullptr, out, zpage);
    }
}